// Round 4
// baseline (138.958 us; speedup 1.0000x reference)
//
#include <hip/hip_runtime.h>

typedef unsigned short u16;
typedef __bf16 bf16;
typedef bf16 bf16x8 __attribute__((ext_vector_type(8)));
typedef float f32x4 __attribute__((ext_vector_type(4)));

#define S 2048
#define D 64
#define BATCH 4
#define SCL 0.022097086912079612f  /* 1/sqrt(2048) */

__device__ __forceinline__ u16 f2bf(float f) {
  union { float f; unsigned u; } v; v.f = f;
  return (u16)((v.u + 0x7FFFu + ((v.u >> 16) & 1u)) >> 16);
}

__device__ __forceinline__ void gld16(const u16* g, u16* l) {
  __builtin_amdgcn_global_load_lds(
      (const __attribute__((address_space(1))) unsigned int*)(const void*)g,
      (__attribute__((address_space(3))) unsigned int*)(void*)l, 16, 0, 0);
}

// ---- 0. W_Q, W_V -> bf16 (one-time stream) ------------------------------
__global__ void k_cvtw(const float* __restrict__ wq, const float* __restrict__ wv,
                       u16* __restrict__ wqb, u16* __restrict__ wvb) {
  const size_t N = (size_t)S * S;
  size_t idx = ((size_t)blockIdx.x * 256 + threadIdx.x) * 8;
  const float* src; u16* dst;
  if (idx < N) { src = wq + idx; dst = wqb + idx; }
  else         { src = wv + (idx - N); dst = wvb + (idx - N); }
  float4 a = *(const float4*)src;
  float4 b = *(const float4*)(src + 4);
  union { u16 s[8]; uint4 v; } u;
  u.s[0]=f2bf(a.x); u.s[1]=f2bf(a.y); u.s[2]=f2bf(a.z); u.s[3]=f2bf(a.w);
  u.s[4]=f2bf(b.x); u.s[5]=f2bf(b.y); u.s[6]=f2bf(b.z); u.s[7]=f2bf(b.w);
  *(uint4*)dst = u.v;
}

// ---- 1. chunk sums (16 rows/chunk) + x -> bf16 (row-major and transposed)
__global__ void k_scan_a(const float* __restrict__ x, u16* __restrict__ xb,
                         u16* __restrict__ xTb, float* __restrict__ csum) {
  int chunk = blockIdx.x, b = blockIdx.y, d = threadIdx.x;
  const float* xp = x + ((size_t)b * S + (size_t)chunk * 16) * D + d;
  float sum = 0.f;
#pragma unroll
  for (int s = 0; s < 16; ++s) {
    float v = xp[(size_t)s * D];
    sum += v;
    int sg = chunk * 16 + s;
    u16 h = f2bf(v);
    xb[((size_t)b * S + sg) * D + d] = h;
    xTb[((size_t)b * D + d) * S + sg] = h;
  }
  csum[((size_t)b * 128 + chunk) * 64 + d] = sum;
}

// ---- 2. finish scan -> GT (running mean, transposed, bf16) --------------
__global__ void k_scan_b(const float* __restrict__ x, const float* __restrict__ csum,
                         u16* __restrict__ GTb) {
  int chunk = blockIdx.x, b = blockIdx.y, d = threadIdx.x;
  float run = 0.f;
  for (int c = 0; c < chunk; ++c) run += csum[((size_t)b * 128 + c) * 64 + d];
  const float* xp = x + ((size_t)b * S + (size_t)chunk * 16) * D + d;
#pragma unroll
  for (int s = 0; s < 16; ++s) {
    run += xp[(size_t)s * D];
    int sg = chunk * 16 + s;
    GTb[((size_t)b * D + d) * S + sg] = f2bf(run / (float)(sg + 1));
  }
}

// ---- 3. batch-packed W-GEMM: Psum[mat][m][n] = W_mat @ BT, n = b*64+d ----
// GTb/xTb's [b][d][s] layout IS BT[n=256][k=2048]. W read once total.
// Tile: 128M x 64N, BK=64, split-K x4, LDS double-buffer via global_load_lds
// with pre-swizzled source (slot sb holds col-block sb^(row&7)).
__global__ __launch_bounds__(256) void k_wgemm(
    const u16* __restrict__ wqb, const u16* __restrict__ wvb,
    const u16* __restrict__ GTb, const u16* __restrict__ xTb,
    float* __restrict__ Psum) {
  __shared__ u16 Ab[2][128 * 64];  // 32 KB
  __shared__ u16 Bb[2][64 * 64];   // 16 KB
  int bx = blockIdx.x;
  int nt = bx & 3, mt = (bx >> 2) & 15, mat = (bx >> 6) & 1, kc = bx >> 7;
  int t = threadIdx.x;
  int w = t >> 6, l = t & 63;
  int lr = l & 15, lg = l >> 4;
  const u16* Wmat = mat ? wvb : wqb;
  const u16* BT = mat ? xTb : GTb;
  // staging addressing (per thread)
  int rA = t >> 3;              // 0..31: row within a 32-row issue
  int sb = t & 7;               // 16B slot within 128B row
  int swz = (sb ^ (rA & 7)) * 8;  // source column elements (pre-swizzle)
  const u16* Ag = Wmat + ((size_t)(mt * 128) + rA) * 2048 + kc * 512 + swz;
  const u16* Bg = BT + ((size_t)(nt * 64) + rA) * 2048 + kc * 512 + swz;
  u16* AL = &Ab[0][0] + w * 512 + (l & 63) * 0;  // base; per-issue offset added below
  f32x4 acc[2][4] = {};

  auto stage = [&](int buf, int kt) {
    const u16* ag = Ag + kt * 64;
    const u16* bg = Bg + kt * 64;
#pragma unroll
    for (int i = 0; i < 4; ++i)
      gld16(ag + (size_t)i * 32 * 2048, &Ab[buf][i * 2048 + w * 512]);
#pragma unroll
    for (int i = 0; i < 2; ++i)
      gld16(bg + (size_t)i * 32 * 2048, &Bb[buf][i * 2048 + w * 512]);
  };

  stage(0, 0);
  __syncthreads();
  int buf = 0;
  for (int kt = 0; kt < 8; ++kt) {
    if (kt < 7) stage(buf ^ 1, kt + 1);
    // fragments from swizzled LDS
    bf16x8 af[2][2], bfv[4][2];
#pragma unroll
    for (int mf = 0; mf < 2; ++mf)
#pragma unroll
      for (int ks = 0; ks < 2; ++ks) {
        int row = w * 32 + mf * 16 + lr;
        af[mf][ks] = *(const bf16x8*)&Ab[buf][row * 64 + (((ks * 4 + lg) ^ (lr & 7)) * 8)];
      }
#pragma unroll
    for (int nf = 0; nf < 4; ++nf)
#pragma unroll
      for (int ks = 0; ks < 2; ++ks) {
        int row = nf * 16 + lr;
        bfv[nf][ks] = *(const bf16x8*)&Bb[buf][row * 64 + (((ks * 4 + lg) ^ (lr & 7)) * 8)];
      }
#pragma unroll
    for (int ks = 0; ks < 2; ++ks)
#pragma unroll
      for (int mf = 0; mf < 2; ++mf)
#pragma unroll
        for (int nf = 0; nf < 4; ++nf)
          acc[mf][nf] = __builtin_amdgcn_mfma_f32_16x16x32_bf16(af[mf][ks], bfv[nf][ks], acc[mf][nf], 0, 0, 0);
    __syncthreads();
    buf ^= 1;
  }
  // split-K accumulate into Psum[mat][m][n]
#pragma unroll
  for (int mf = 0; mf < 2; ++mf)
#pragma unroll
    for (int nf = 0; nf < 4; ++nf)
#pragma unroll
      for (int r = 0; r < 4; ++r) {
        int m = mt * 128 + w * 32 + mf * 16 + lg * 4 + r;
        int n = nt * 64 + nf * 16 + lr;
        atomicAdd(&Psum[((size_t)mat * S + m) * 256 + n], acc[mf][nf][r]);
      }
}

// ---- 4. finalize: Psum -> Qb (row-major) and VTb (transposed) bf16 ------
__global__ __launch_bounds__(256) void k_fin(
    const float* __restrict__ Psum, u16* __restrict__ Qb, u16* __restrict__ VTb) {
  __shared__ u16 T[64][260];
  int mt2 = blockIdx.x, mat = blockIdx.y;
  int t = threadIdx.x;
  int b = t >> 6, d = t & 63;
#pragma unroll 4
  for (int mi = 0; mi < 64; ++mi) {
    int m = mt2 * 64 + mi;
    float s = Psum[((size_t)mat * S + m) * 256 + t];
    u16 h = f2bf(s);
    if (mat == 0) Qb[((size_t)b * S + m) * D + d] = h;
    else T[mi][t] = h;
  }
  if (mat == 1) {
    __syncthreads();
    u16* dst = VTb + ((size_t)b * D + d) * S + mt2 * 64;
#pragma unroll
    for (int c = 0; c < 8; ++c) {
      union { u16 s[8]; uint4 v; } u;
#pragma unroll
      for (int e = 0; e < 8; ++e) u.s[e] = T[c * 8 + e][t];
      *(uint4*)(dst + c * 8) = u.v;
    }
  }
}

// ---- 5. column stats: m_j, Z_j over i>=j ---------------------------------
__global__ __launch_bounds__(256) void k_stats(
    const u16* __restrict__ xb, const u16* __restrict__ Qb,
    float* __restrict__ mbuf, float* __restrict__ rzbuf) {
  __shared__ float ms[4][16], zs[4][16];
  int jg = blockIdx.x, b = blockIdx.y;
  int tid = threadIdx.x;
  int w = tid >> 6, l = tid & 63;
  int lr = l & 15, lg = l >> 4;
  int j0 = jg * 16;
  const u16* xbase = xb + (size_t)b * S * D;
  const u16* qbase = Qb + (size_t)b * S * D;
  bf16x8 xa0 = *(const bf16x8*)(xbase + (size_t)(j0 + lr) * D + lg * 8);
  bf16x8 xa1 = *(const bf16x8*)(xbase + (size_t)(j0 + lr) * D + 32 + lg * 8);
  float m[4] = {-1e30f, -1e30f, -1e30f, -1e30f};
  float z[4] = {0.f, 0.f, 0.f, 0.f};
  for (int i16 = j0 + w * 16; i16 < S; i16 += 64) {
    bf16x8 q0 = *(const bf16x8*)(qbase + (size_t)(i16 + lr) * D + lg * 8);
    bf16x8 q1 = *(const bf16x8*)(qbase + (size_t)(i16 + lr) * D + 32 + lg * 8);
    f32x4 c = {};
    c = __builtin_amdgcn_mfma_f32_16x16x32_bf16(xa0, q0, c, 0, 0, 0);
    c = __builtin_amdgcn_mfma_f32_16x16x32_bf16(xa1, q1, c, 0, 0, 0);
    int i = i16 + lr;
#pragma unroll
    for (int r = 0; r < 4; ++r) {
      int j = j0 + lg * 4 + r;
      float sc = c[r];
      float a = (i >= j && sc > 1.0f) ? sc * SCL : -1e30f;
      float mn = fmaxf(m[r], a);
      z[r] = z[r] * __expf(m[r] - mn) + __expf(a - mn);
      m[r] = mn;
    }
  }
#pragma unroll
  for (int r = 0; r < 4; ++r) {
#pragma unroll
    for (int s = 1; s < 16; s <<= 1) {
      float mo = __shfl_xor(m[r], s);
      float zo = __shfl_xor(z[r], s);
      float mn = fmaxf(m[r], mo);
      z[r] = z[r] * __expf(m[r] - mn) + zo * __expf(mo - mn);
      m[r] = mn;
    }
  }
  if (lr == 0) {
#pragma unroll
    for (int r = 0; r < 4; ++r) {
      ms[w][lg * 4 + r] = m[r];
      zs[w][lg * 4 + r] = z[r];
    }
  }
  __syncthreads();
  if (tid < 16) {
    float mf = -1e30f;
#pragma unroll
    for (int ww = 0; ww < 4; ++ww) mf = fmaxf(mf, ms[ww][tid]);
    float zf = 0.f;
#pragma unroll
    for (int ww = 0; ww < 4; ++ww) zf += zs[ww][tid] * __expf(ms[ww][tid] - mf);
    mbuf[(size_t)b * S + j0 + tid] = mf;
    rzbuf[(size_t)b * S + j0 + tid] = 1.0f / zf;
  }
}

// ---- 6. out += P_chunk @ V_chunk. One block per (i-tile, 4-j-tile chunk).
__global__ __launch_bounds__(256) void k_out(
    const u16* __restrict__ xb, const u16* __restrict__ Qb, const u16* __restrict__ VTb,
    const float* __restrict__ mbuf, const float* __restrict__ rzbuf,
    float* __restrict__ out) {
  __shared__ u16 Plds[4][16][72];
  int bx = blockIdx.x, b = blockIdx.y;
  int it = 0, jc = 0, base = 0;
  for (int tt = 0; tt < 32; ++tt) {
    int nc = (tt + 4) >> 2;
    if (bx < base + nc) { it = tt; jc = bx - base; break; }
    base += nc;
  }
  int w = threadIdx.x >> 6, l = threadIdx.x & 63;
  int lr = l & 15, lg = l >> 4;
  int i0 = it * 64 + w * 16;
  const u16* xbase = xb + (size_t)b * S * D;
  const u16* qbase = Qb + (size_t)b * S * D;
  const u16* vbase = VTb + (size_t)b * D * S;
  const float* mb = mbuf + (size_t)b * S;
  const float* rzb = rzbuf + (size_t)b * S;
  bf16x8 qa0 = *(const bf16x8*)(qbase + (size_t)(i0 + lr) * D + lg * 8);
  bf16x8 qa1 = *(const bf16x8*)(qbase + (size_t)(i0 + lr) * D + 32 + lg * 8);
  f32x4 acc[4] = {};
  int jt_end = min(jc * 4 + 4, it + 1);
  for (int jt = jc * 4; jt < jt_end; ++jt) {
#pragma unroll
    for (int js = 0; js < 4; ++js) {
      int j16 = jt * 64 + js * 16;
      bf16x8 xb0 = *(const bf16x8*)(xbase + (size_t)(j16 + lr) * D + lg * 8);
      bf16x8 xb1 = *(const bf16x8*)(xbase + (size_t)(j16 + lr) * D + 32 + lg * 8);
      f32x4 c = {};
      c = __builtin_amdgcn_mfma_f32_16x16x32_bf16(qa0, xb0, c, 0, 0, 0);
      c = __builtin_amdgcn_mfma_f32_16x16x32_bf16(qa1, xb1, c, 0, 0, 0);
      int j = j16 + lr;
      float mj = mb[j];
      float rzj = rzb[j];
#pragma unroll
      for (int r = 0; r < 4; ++r) {
        int i = i0 + lg * 4 + r;
        float sc = c[r];
        float a = (j <= i && sc > 1.0f) ? sc * SCL : -1e30f;
        float wgt = __expf(a - mj) * rzj;
        Plds[w][lg * 4 + r][js * 16 + lr] = f2bf(wgt);
      }
    }
    asm volatile("s_waitcnt lgkmcnt(0)" ::: "memory");
#pragma unroll
    for (int kk = 0; kk < 2; ++kk) {
      bf16x8 pa = *(const bf16x8*)(&Plds[w][lr][kk * 32 + lg * 8]);
#pragma unroll
      for (int dt = 0; dt < 4; ++dt) {
        bf16x8 vbf = *(const bf16x8*)(vbase + (size_t)(dt * 16 + lr) * S + jt * 64 + kk * 32 + lg * 8);
        acc[dt] = __builtin_amdgcn_mfma_f32_16x16x32_bf16(pa, vbf, acc[dt], 0, 0, 0);
      }
    }
    asm volatile("s_waitcnt lgkmcnt(0)" ::: "memory");
  }
  float* obase = out + (size_t)b * S * D;
#pragma unroll
  for (int dt = 0; dt < 4; ++dt)
#pragma unroll
    for (int r = 0; r < 4; ++r) {
      int i = i0 + lg * 4 + r;
      atomicAdd(&obase[(size_t)i * D + dt * 16 + lr], acc[dt][r]);
    }
}

extern "C" void kernel_launch(void* const* d_in, const int* in_sizes, int n_in,
                              void* d_out, int out_size, void* d_ws, size_t ws_size,
                              hipStream_t stream) {
  const float* x  = (const float*)d_in[0];
  const float* wq = (const float*)d_in[1];
  const float* wv = (const float*)d_in[2];
  float* out = (float*)d_out;
  char* ws = (char*)d_ws;
  size_t off = 0;
  auto alloc = [&](size_t bytes) -> void* {
    void* p = ws + off; off += (bytes + 255) & ~255ULL; return p;
  };
  u16* xb   = (u16*)alloc((size_t)BATCH * S * D * 2);
  u16* xTb  = (u16*)alloc((size_t)BATCH * S * D * 2);
  u16* GTb  = (u16*)alloc((size_t)BATCH * S * D * 2);
  u16* Qb   = (u16*)alloc((size_t)BATCH * S * D * 2);
  u16* VTb  = (u16*)alloc((size_t)BATCH * S * D * 2);
  float* csum  = (float*)alloc((size_t)BATCH * 128 * 64 * 4);
  float* mbuf  = (float*)alloc((size_t)BATCH * S * 4);
  float* rzbuf = (float*)alloc((size_t)BATCH * S * 4);
  u16* wqb  = (u16*)alloc((size_t)S * S * 2);
  u16* wvb  = (u16*)alloc((size_t)S * S * 2);
  float* Psum = (float*)alloc((size_t)2 * S * 256 * 4);

  hipMemsetAsync(Psum, 0, (size_t)2 * S * 256 * 4, stream);
  hipMemsetAsync(out, 0, (size_t)out_size * 4, stream);
  k_cvtw<<<4096, 256, 0, stream>>>(wq, wv, wqb, wvb);
  k_scan_a<<<dim3(128, BATCH), 64, 0, stream>>>(x, xb, xTb, csum);
  k_scan_b<<<dim3(128, BATCH), 64, 0, stream>>>(x, csum, GTb);
  k_wgemm<<<512, 256, 0, stream>>>(wqb, wvb, GTb, xTb, Psum);
  k_fin<<<dim3(32, 2), 256, 0, stream>>>(Psum, Qb, VTb);
  k_stats<<<dim3(128, BATCH), 256, 0, stream>>>(xb, Qb, mbuf, rzbuf);
  k_out<<<dim3(144, BATCH), 256, 0, stream>>>(xb, Qb, VTb, mbuf, rzbuf, out);
}

// Round 5
// 131.685 us; speedup vs baseline: 1.0552x; 1.0552x over previous
//
#include <hip/hip_runtime.h>

typedef unsigned short u16;
typedef __bf16 bf16;
typedef bf16 bf16x8 __attribute__((ext_vector_type(8)));
typedef float f32x4 __attribute__((ext_vector_type(4)));

#define S 2048
#define D 64
#define BATCH 4
#define SCL 0.022097086912079612f  /* 1/sqrt(2048) */

__device__ __forceinline__ u16 f2bf(float f) {
  union { float f; unsigned u; } v; v.f = f;
  return (u16)((v.u + 0x7FFFu + ((v.u >> 16) & 1u)) >> 16);
}

__device__ __forceinline__ void gld16(const u16* g, u16* l) {
  __builtin_amdgcn_global_load_lds(
      (const __attribute__((address_space(1))) unsigned int*)(const void*)g,
      (__attribute__((address_space(3))) unsigned int*)(void*)l, 16, 0, 0);
}

// ---- 0a. zero d_out (own kernel: rocclr fill was 40us latency-bound) ----
__global__ void k_zero(float* __restrict__ p) {
  size_t i = ((size_t)blockIdx.x * 256 + threadIdx.x) * 4;
  *(float4*)(p + i) = make_float4(0.f, 0.f, 0.f, 0.f);
}

// ---- 0b. W_Q, W_V -> bf16 (one-time stream) -----------------------------
__global__ void k_cvtw(const float* __restrict__ wq, const float* __restrict__ wv,
                       u16* __restrict__ wqb, u16* __restrict__ wvb) {
  const size_t N = (size_t)S * S;
  size_t idx = ((size_t)blockIdx.x * 256 + threadIdx.x) * 8;
  const float* src; u16* dst;
  if (idx < N) { src = wq + idx; dst = wqb + idx; }
  else         { src = wv + (idx - N); dst = wvb + (idx - N); }
  float4 a = *(const float4*)src;
  float4 b = *(const float4*)(src + 4);
  union { u16 s[8]; uint4 v; } u;
  u.s[0]=f2bf(a.x); u.s[1]=f2bf(a.y); u.s[2]=f2bf(a.z); u.s[3]=f2bf(a.w);
  u.s[4]=f2bf(b.x); u.s[5]=f2bf(b.y); u.s[6]=f2bf(b.z); u.s[7]=f2bf(b.w);
  *(uint4*)dst = u.v;
}

// ---- 1. chunk sums (16 rows/chunk) + x -> bf16 (row-major and transposed)
__global__ void k_scan_a(const float* __restrict__ x, u16* __restrict__ xb,
                         u16* __restrict__ xTb, float* __restrict__ csum) {
  int chunk = blockIdx.x, b = blockIdx.y, d = threadIdx.x;
  const float* xp = x + ((size_t)b * S + (size_t)chunk * 16) * D + d;
  float sum = 0.f;
#pragma unroll
  for (int s = 0; s < 16; ++s) {
    float v = xp[(size_t)s * D];
    sum += v;
    int sg = chunk * 16 + s;
    u16 h = f2bf(v);
    xb[((size_t)b * S + sg) * D + d] = h;
    xTb[((size_t)b * D + d) * S + sg] = h;
  }
  csum[((size_t)b * 128 + chunk) * 64 + d] = sum;
}

// ---- 2. finish scan -> GT (running mean, transposed, bf16) --------------
__global__ void k_scan_b(const float* __restrict__ x, const float* __restrict__ csum,
                         u16* __restrict__ GTb) {
  int chunk = blockIdx.x, b = blockIdx.y, d = threadIdx.x;
  float run = 0.f;
  for (int c = 0; c < chunk; ++c) run += csum[((size_t)b * 128 + c) * 64 + d];
  const float* xp = x + ((size_t)b * S + (size_t)chunk * 16) * D + d;
#pragma unroll
  for (int s = 0; s < 16; ++s) {
    run += xp[(size_t)s * D];
    int sg = chunk * 16 + s;
    GTb[((size_t)b * D + d) * S + sg] = f2bf(run / (float)(sg + 1));
  }
}

// ---- 3. batch-packed W-GEMM: Psum[kc][mat][m][n] = partial W_mat @ BT ----
// GTb/xTb's [b][d][s] layout IS BT[n=256][k=2048]. W read once total.
// Tile: 128M x 64N, BK=64, split-K x4 -> disjoint stores (no memset needed).
__global__ __launch_bounds__(256) void k_wgemm(
    const u16* __restrict__ wqb, const u16* __restrict__ wvb,
    const u16* __restrict__ GTb, const u16* __restrict__ xTb,
    float* __restrict__ Psum) {
  __shared__ u16 Ab[2][128 * 64];  // 32 KB
  __shared__ u16 Bb[2][64 * 64];   // 16 KB
  int bx = blockIdx.x;
  int nt = bx & 3, mt = (bx >> 2) & 15, mat = (bx >> 6) & 1, kc = bx >> 7;
  int t = threadIdx.x;
  int w = t >> 6, l = t & 63;
  int lr = l & 15, lg = l >> 4;
  const u16* Wmat = mat ? wvb : wqb;
  const u16* BT = mat ? xTb : GTb;
  // staging addressing (per thread)
  int rA = t >> 3;                // 0..31: row within a 32-row issue
  int sb = t & 7;                 // 16B slot within 128B row
  int swz = (sb ^ (rA & 7)) * 8;  // source column elements (pre-swizzle)
  const u16* Ag = Wmat + ((size_t)(mt * 128) + rA) * 2048 + kc * 512 + swz;
  const u16* Bg = BT + ((size_t)(nt * 64) + rA) * 2048 + kc * 512 + swz;
  f32x4 acc[2][4] = {};

  auto stage = [&](int buf, int kt) {
    const u16* ag = Ag + kt * 64;
    const u16* bg = Bg + kt * 64;
#pragma unroll
    for (int i = 0; i < 4; ++i)
      gld16(ag + (size_t)i * 32 * 2048, &Ab[buf][i * 2048 + w * 512]);
#pragma unroll
    for (int i = 0; i < 2; ++i)
      gld16(bg + (size_t)i * 32 * 2048, &Bb[buf][i * 2048 + w * 512]);
  };

  stage(0, 0);
  __syncthreads();
  int buf = 0;
  for (int kt = 0; kt < 8; ++kt) {
    if (kt < 7) stage(buf ^ 1, kt + 1);
    bf16x8 af[2][2], bfv[4][2];
#pragma unroll
    for (int mf = 0; mf < 2; ++mf)
#pragma unroll
      for (int ks = 0; ks < 2; ++ks) {
        int row = w * 32 + mf * 16 + lr;
        af[mf][ks] = *(const bf16x8*)&Ab[buf][row * 64 + (((ks * 4 + lg) ^ (lr & 7)) * 8)];
      }
#pragma unroll
    for (int nf = 0; nf < 4; ++nf)
#pragma unroll
      for (int ks = 0; ks < 2; ++ks) {
        int row = nf * 16 + lr;
        bfv[nf][ks] = *(const bf16x8*)&Bb[buf][row * 64 + (((ks * 4 + lg) ^ (lr & 7)) * 8)];
      }
#pragma unroll
    for (int ks = 0; ks < 2; ++ks)
#pragma unroll
      for (int mf = 0; mf < 2; ++mf)
#pragma unroll
        for (int nf = 0; nf < 4; ++nf)
          acc[mf][nf] = __builtin_amdgcn_mfma_f32_16x16x32_bf16(af[mf][ks], bfv[nf][ks], acc[mf][nf], 0, 0, 0);
    __syncthreads();
    buf ^= 1;
  }
  // disjoint partial store: Psum[kc][mat][m][n]
  float* P = Psum + (((size_t)kc * 2 + mat) * S) * 256;
#pragma unroll
  for (int mf = 0; mf < 2; ++mf)
#pragma unroll
    for (int nf = 0; nf < 4; ++nf)
#pragma unroll
      for (int r = 0; r < 4; ++r) {
        int m = mt * 128 + w * 32 + mf * 16 + lg * 4 + r;
        int n = nt * 64 + nf * 16 + lr;
        P[(size_t)m * 256 + n] = acc[mf][nf][r];
      }
}

// ---- 4. finalize: sum 4 split-K slices -> Qb (row-major), VTb (transposed)
__global__ __launch_bounds__(256) void k_fin(
    const float* __restrict__ Psum, u16* __restrict__ Qb, u16* __restrict__ VTb) {
  __shared__ u16 T[64][260];
  int mt2 = blockIdx.x, mat = blockIdx.y;
  int t = threadIdx.x;
  int b = t >> 6, d = t & 63;
  const size_t slice = (size_t)2 * S * 256;
#pragma unroll 4
  for (int mi = 0; mi < 64; ++mi) {
    int m = mt2 * 64 + mi;
    size_t base = ((size_t)mat * S + m) * 256 + t;
    float s = Psum[base] + Psum[base + slice] + Psum[base + 2 * slice] + Psum[base + 3 * slice];
    u16 h = f2bf(s);
    if (mat == 0) Qb[((size_t)b * S + m) * D + d] = h;
    else T[mi][t] = h;
  }
  if (mat == 1) {
    __syncthreads();
    u16* dst = VTb + ((size_t)b * D + d) * S + mt2 * 64;
#pragma unroll
    for (int c = 0; c < 8; ++c) {
      union { u16 s[8]; uint4 v; } u;
#pragma unroll
      for (int e = 0; e < 8; ++e) u.s[e] = T[c * 8 + e][t];
      *(uint4*)(dst + c * 8) = u.v;
    }
  }
}

// ---- 5. column stats: m_j, Z_j over i>=j ---------------------------------
__global__ __launch_bounds__(256) void k_stats(
    const u16* __restrict__ xb, const u16* __restrict__ Qb,
    float* __restrict__ mbuf, float* __restrict__ rzbuf) {
  __shared__ float ms[4][16], zs[4][16];
  int jg = blockIdx.x, b = blockIdx.y;
  int tid = threadIdx.x;
  int w = tid >> 6, l = tid & 63;
  int lr = l & 15, lg = l >> 4;
  int j0 = jg * 16;
  const u16* xbase = xb + (size_t)b * S * D;
  const u16* qbase = Qb + (size_t)b * S * D;
  bf16x8 xa0 = *(const bf16x8*)(xbase + (size_t)(j0 + lr) * D + lg * 8);
  bf16x8 xa1 = *(const bf16x8*)(xbase + (size_t)(j0 + lr) * D + 32 + lg * 8);
  float m[4] = {-1e30f, -1e30f, -1e30f, -1e30f};
  float z[4] = {0.f, 0.f, 0.f, 0.f};
  for (int i16 = j0 + w * 16; i16 < S; i16 += 64) {
    bf16x8 q0 = *(const bf16x8*)(qbase + (size_t)(i16 + lr) * D + lg * 8);
    bf16x8 q1 = *(const bf16x8*)(qbase + (size_t)(i16 + lr) * D + 32 + lg * 8);
    f32x4 c = {};
    c = __builtin_amdgcn_mfma_f32_16x16x32_bf16(xa0, q0, c, 0, 0, 0);
    c = __builtin_amdgcn_mfma_f32_16x16x32_bf16(xa1, q1, c, 0, 0, 0);
    int i = i16 + lr;
#pragma unroll
    for (int r = 0; r < 4; ++r) {
      int j = j0 + lg * 4 + r;
      float sc = c[r];
      float a = (i >= j && sc > 1.0f) ? sc * SCL : -1e30f;
      float mn = fmaxf(m[r], a);
      z[r] = z[r] * __expf(m[r] - mn) + __expf(a - mn);
      m[r] = mn;
    }
  }
#pragma unroll
  for (int r = 0; r < 4; ++r) {
#pragma unroll
    for (int s = 1; s < 16; s <<= 1) {
      float mo = __shfl_xor(m[r], s);
      float zo = __shfl_xor(z[r], s);
      float mn = fmaxf(m[r], mo);
      z[r] = z[r] * __expf(m[r] - mn) + zo * __expf(mo - mn);
      m[r] = mn;
    }
  }
  if (lr == 0) {
#pragma unroll
    for (int r = 0; r < 4; ++r) {
      ms[w][lg * 4 + r] = m[r];
      zs[w][lg * 4 + r] = z[r];
    }
  }
  __syncthreads();
  if (tid < 16) {
    float mf = -1e30f;
#pragma unroll
    for (int ww = 0; ww < 4; ++ww) mf = fmaxf(mf, ms[ww][tid]);
    float zf = 0.f;
#pragma unroll
    for (int ww = 0; ww < 4; ++ww) zf += zs[ww][tid] * __expf(ms[ww][tid] - mf);
    mbuf[(size_t)b * S + j0 + tid] = mf;
    rzbuf[(size_t)b * S + j0 + tid] = 1.0f / zf;
  }
}

// ---- 6. out += P_chunk @ V_chunk. One block per (i-tile, 4-j-tile chunk).
__global__ __launch_bounds__(256) void k_out(
    const u16* __restrict__ xb, const u16* __restrict__ Qb, const u16* __restrict__ VTb,
    const float* __restrict__ mbuf, const float* __restrict__ rzbuf,
    float* __restrict__ out) {
  __shared__ u16 Plds[4][16][72];
  int bx = blockIdx.x, b = blockIdx.y;
  int it = 0, jc = 0, base = 0;
  for (int tt = 0; tt < 32; ++tt) {
    int nc = (tt + 4) >> 2;
    if (bx < base + nc) { it = tt; jc = bx - base; break; }
    base += nc;
  }
  int w = threadIdx.x >> 6, l = threadIdx.x & 63;
  int lr = l & 15, lg = l >> 4;
  int i0 = it * 64 + w * 16;
  const u16* xbase = xb + (size_t)b * S * D;
  const u16* qbase = Qb + (size_t)b * S * D;
  const u16* vbase = VTb + (size_t)b * D * S;
  const float* mb = mbuf + (size_t)b * S;
  const float* rzb = rzbuf + (size_t)b * S;
  bf16x8 qa0 = *(const bf16x8*)(qbase + (size_t)(i0 + lr) * D + lg * 8);
  bf16x8 qa1 = *(const bf16x8*)(qbase + (size_t)(i0 + lr) * D + 32 + lg * 8);
  f32x4 acc[4] = {};
  int jt_end = min(jc * 4 + 4, it + 1);
  for (int jt = jc * 4; jt < jt_end; ++jt) {
#pragma unroll
    for (int js = 0; js < 4; ++js) {
      int j16 = jt * 64 + js * 16;
      bf16x8 xb0 = *(const bf16x8*)(xbase + (size_t)(j16 + lr) * D + lg * 8);
      bf16x8 xb1 = *(const bf16x8*)(xbase + (size_t)(j16 + lr) * D + 32 + lg * 8);
      f32x4 c = {};
      c = __builtin_amdgcn_mfma_f32_16x16x32_bf16(qa0, xb0, c, 0, 0, 0);
      c = __builtin_amdgcn_mfma_f32_16x16x32_bf16(qa1, xb1, c, 0, 0, 0);
      int j = j16 + lr;
      float mj = mb[j];
      float rzj = rzb[j];
#pragma unroll
      for (int r = 0; r < 4; ++r) {
        int i = i0 + lg * 4 + r;
        float sc = c[r];
        float a = (j <= i && sc > 1.0f) ? sc * SCL : -1e30f;
        float wgt = __expf(a - mj) * rzj;
        Plds[w][lg * 4 + r][js * 16 + lr] = f2bf(wgt);
      }
    }
    asm volatile("s_waitcnt lgkmcnt(0)" ::: "memory");
#pragma unroll
    for (int kk = 0; kk < 2; ++kk) {
      bf16x8 pa = *(const bf16x8*)(&Plds[w][lr][kk * 32 + lg * 8]);
#pragma unroll
      for (int dt = 0; dt < 4; ++dt) {
        bf16x8 vbf = *(const bf16x8*)(vbase + (size_t)(dt * 16 + lr) * S + jt * 64 + kk * 32 + lg * 8);
        acc[dt] = __builtin_amdgcn_mfma_f32_16x16x32_bf16(pa, vbf, acc[dt], 0, 0, 0);
      }
    }
    asm volatile("s_waitcnt lgkmcnt(0)" ::: "memory");
  }
  float* obase = out + (size_t)b * S * D;
#pragma unroll
  for (int dt = 0; dt < 4; ++dt)
#pragma unroll
    for (int r = 0; r < 4; ++r) {
      int i = i0 + lg * 4 + r;
      atomicAdd(&obase[(size_t)i * D + dt * 16 + lr], acc[dt][r]);
    }
}

extern "C" void kernel_launch(void* const* d_in, const int* in_sizes, int n_in,
                              void* d_out, int out_size, void* d_ws, size_t ws_size,
                              hipStream_t stream) {
  const float* x  = (const float*)d_in[0];
  const float* wq = (const float*)d_in[1];
  const float* wv = (const float*)d_in[2];
  float* out = (float*)d_out;
  char* ws = (char*)d_ws;
  size_t off = 0;
  auto alloc = [&](size_t bytes) -> void* {
    void* p = ws + off; off += (bytes + 255) & ~255ULL; return p;
  };
  u16* xb   = (u16*)alloc((size_t)BATCH * S * D * 2);
  u16* xTb  = (u16*)alloc((size_t)BATCH * S * D * 2);
  u16* GTb  = (u16*)alloc((size_t)BATCH * S * D * 2);
  u16* Qb   = (u16*)alloc((size_t)BATCH * S * D * 2);
  u16* VTb  = (u16*)alloc((size_t)BATCH * S * D * 2);
  float* csum  = (float*)alloc((size_t)BATCH * 128 * 64 * 4);
  float* mbuf  = (float*)alloc((size_t)BATCH * S * 4);
  float* rzbuf = (float*)alloc((size_t)BATCH * S * 4);
  u16* wqb  = (u16*)alloc((size_t)S * S * 2);
  u16* wvb  = (u16*)alloc((size_t)S * S * 2);
  float* Psum = (float*)alloc((size_t)4 * 2 * S * 256 * 4);  // [kc][mat][m][n]

  k_zero<<<512, 256, 0, stream>>>(out);
  k_cvtw<<<4096, 256, 0, stream>>>(wq, wv, wqb, wvb);
  k_scan_a<<<dim3(128, BATCH), 64, 0, stream>>>(x, xb, xTb, csum);
  k_scan_b<<<dim3(128, BATCH), 64, 0, stream>>>(x, csum, GTb);
  k_wgemm<<<512, 256, 0, stream>>>(wqb, wvb, GTb, xTb, Psum);
  k_fin<<<dim3(32, 2), 256, 0, stream>>>(Psum, Qb, VTb);
  k_stats<<<dim3(128, BATCH), 256, 0, stream>>>(xb, Qb, mbuf, rzbuf);
  k_out<<<dim3(144, BATCH), 256, 0, stream>>>(xb, Qb, VTb, mbuf, rzbuf, out);
}

// Round 6
// 111.823 us; speedup vs baseline: 1.2427x; 1.1776x over previous
//
#include <hip/hip_runtime.h>

typedef unsigned short u16;
typedef __bf16 bf16;
typedef bf16 bf16x8 __attribute__((ext_vector_type(8)));
typedef float f32x4 __attribute__((ext_vector_type(4)));

#define S 2048
#define D 64
#define BATCH 4
#define SCL 0.022097086912079612f  /* 1/sqrt(2048) */

__device__ __forceinline__ u16 f2bf(float f) {
  union { float f; unsigned u; } v; v.f = f;
  return (u16)((v.u + 0x7FFFu + ((v.u >> 16) & 1u)) >> 16);
}

__device__ __forceinline__ void gld16(const u16* g, u16* l) {
  __builtin_amdgcn_global_load_lds(
      (const __attribute__((address_space(1))) unsigned int*)(const void*)g,
      (__attribute__((address_space(3))) unsigned int*)(void*)l, 16, 0, 0);
}

// ---- N1: fused {W->bf16 convert | scan-a chunk sums + x->bf16 | zero out}
__global__ void k_pre(const float* __restrict__ x,
                      const float* __restrict__ wq, const float* __restrict__ wv,
                      u16* __restrict__ wqb, u16* __restrict__ wvb,
                      u16* __restrict__ xb, u16* __restrict__ xTb,
                      float* __restrict__ csum, float* __restrict__ out) {
  int bx = blockIdx.x, t = threadIdx.x;
  if (bx < 4096) {                       // W convert: 4096 blocks * 256 * 8 elems
    const size_t N = (size_t)S * S;
    size_t idx = ((size_t)bx * 256 + t) * 8;
    const float* src; u16* dst;
    if (idx < N) { src = wq + idx; dst = wqb + idx; }
    else         { src = wv + (idx - N); dst = wvb + (idx - N); }
    float4 a = *(const float4*)src;
    float4 b = *(const float4*)(src + 4);
    union { u16 s[8]; uint4 v; } u;
    u.s[0]=f2bf(a.x); u.s[1]=f2bf(a.y); u.s[2]=f2bf(a.z); u.s[3]=f2bf(a.w);
    u.s[4]=f2bf(b.x); u.s[5]=f2bf(b.y); u.s[6]=f2bf(b.z); u.s[7]=f2bf(b.w);
    *(uint4*)dst = u.v;
  } else if (bx < 4224) {                // scan-a: 128 blocks * 4 jobs
    int job = (bx - 4096) * 4 + (t >> 6);
    int chunk = job >> 2, b = job & 3, d = t & 63;
    const float* xp = x + ((size_t)b * S + (size_t)chunk * 16) * D + d;
    float sum = 0.f;
#pragma unroll
    for (int s = 0; s < 16; ++s) {
      float v = xp[(size_t)s * D];
      sum += v;
      int sg = chunk * 16 + s;
      u16 h = f2bf(v);
      xb[((size_t)b * S + sg) * D + d] = h;
      xTb[((size_t)b * D + d) * S + sg] = h;
    }
    csum[((size_t)b * 128 + chunk) * 64 + d] = sum;
  } else {                               // zero d_out: 512 blocks * 256 * float4
    size_t i = (((size_t)(bx - 4224) * 256) + t) * 4;
    *(float4*)(out + i) = make_float4(0.f, 0.f, 0.f, 0.f);
  }
}

// ---- N2: finish scan -> GT (running mean, transposed, bf16) -------------
__global__ void k_scanb(const float* __restrict__ x, const float* __restrict__ csum,
                        u16* __restrict__ GTb) {
  int job = blockIdx.x * 4 + (threadIdx.x >> 6);
  int chunk = job >> 2, b = job & 3, d = threadIdx.x & 63;
  float run = 0.f;
  for (int c = 0; c < chunk; ++c) run += csum[((size_t)b * 128 + c) * 64 + d];
  const float* xp = x + ((size_t)b * S + (size_t)chunk * 16) * D + d;
#pragma unroll
  for (int s = 0; s < 16; ++s) {
    run += xp[(size_t)s * D];
    int sg = chunk * 16 + s;
    GTb[((size_t)b * D + d) * S + sg] = f2bf(run / (float)(sg + 1));
  }
}

// ---- N3: W-GEMM, kc=1, no Psum. Tile 64M x 64N, BK=64, 32 K-steps. ------
// bx = nt*64 + (mt*2+mat): nt-siblings (same W panel) land on same XCD.
// Direct epilogue: Qb row-major (mat0), VTb transposed (mat1); n = b*64+d.
__global__ __launch_bounds__(256) void k_wg(
    const u16* __restrict__ wqb, const u16* __restrict__ wvb,
    const u16* __restrict__ GTb, const u16* __restrict__ xTb,
    u16* __restrict__ Qb, u16* __restrict__ VTb) {
  __shared__ u16 Ab[2][64 * 64];  // 16 KB
  __shared__ u16 Bb[2][64 * 64];  // 16 KB
  int bx = blockIdx.x;
  int nt = bx >> 6, mm = bx & 63, mt = mm >> 1, mat = mm & 1;
  int t = threadIdx.x;
  int w = t >> 6, l = t & 63;
  int lr = l & 15, lg = l >> 4;
  const u16* Wmat = mat ? wvb : wqb;
  const u16* BT = mat ? xTb : GTb;
  int rA = t >> 3;                 // 0..31 row within a 32-row issue
  int sb = t & 7;                  // 16B slot within 128B row
  int swz = (sb ^ (rA & 7)) * 8;   // pre-swizzled source column
  const u16* Ag = Wmat + ((size_t)(mt * 64) + rA) * 2048 + swz;
  const u16* Bg = BT + ((size_t)(nt * 64) + rA) * 2048 + swz;
  f32x4 acc[4] = {};

  auto stage = [&](int buf, int kt) {
    const u16* ag = Ag + kt * 64;
    const u16* bg = Bg + kt * 64;
#pragma unroll
    for (int i = 0; i < 2; ++i)
      gld16(ag + (size_t)i * 32 * 2048, &Ab[buf][i * 2048 + w * 512]);
#pragma unroll
    for (int i = 0; i < 2; ++i)
      gld16(bg + (size_t)i * 32 * 2048, &Bb[buf][i * 2048 + w * 512]);
  };

  stage(0, 0);
  __syncthreads();
  int buf = 0;
  for (int kt = 0; kt < 32; ++kt) {
    if (kt < 31) stage(buf ^ 1, kt + 1);
    bf16x8 af[2], bfv[4][2];
#pragma unroll
    for (int ks = 0; ks < 2; ++ks) {
      int row = w * 16 + lr;
      af[ks] = *(const bf16x8*)&Ab[buf][row * 64 + (((ks * 4 + lg) ^ (lr & 7)) * 8)];
    }
#pragma unroll
    for (int nf = 0; nf < 4; ++nf)
#pragma unroll
      for (int ks = 0; ks < 2; ++ks) {
        int row = nf * 16 + lr;
        bfv[nf][ks] = *(const bf16x8*)&Bb[buf][row * 64 + (((ks * 4 + lg) ^ (lr & 7)) * 8)];
      }
#pragma unroll
    for (int ks = 0; ks < 2; ++ks)
#pragma unroll
      for (int nf = 0; nf < 4; ++nf)
        acc[nf] = __builtin_amdgcn_mfma_f32_16x16x32_bf16(af[ks], bfv[nf][ks], acc[nf], 0, 0, 0);
    __syncthreads();
    buf ^= 1;
  }
  // epilogue: m = mt*64 + w*16 + lg*4 + r; n = nt*64 + nf*16 + lr; b = nt.
  int mbase = mt * 64 + w * 16 + lg * 4;
  if (mat == 0) {
#pragma unroll
    for (int nf = 0; nf < 4; ++nf)
#pragma unroll
      for (int r = 0; r < 4; ++r)
        Qb[((size_t)nt * S + mbase + r) * D + nf * 16 + lr] = f2bf(acc[nf][r]);
  } else {
#pragma unroll
    for (int nf = 0; nf < 4; ++nf) {
      union { u16 s[4]; ushort4 v; } u;
#pragma unroll
      for (int r = 0; r < 4; ++r) u.s[r] = f2bf(acc[nf][r]);
      *(ushort4*)&VTb[((size_t)nt * D + nf * 16 + lr) * S + mbase] = u.v;
    }
  }
}

// ---- N4: column sums Z_j = sum_{i>=j, sc>1} exp(sc*SCL). No max needed:
// scores are bounded (<~50 after scaling) so fp32 exp cannot overflow.
__global__ __launch_bounds__(256) void k_stats(
    const u16* __restrict__ xb, const u16* __restrict__ Qb,
    float* __restrict__ rzbuf) {
  __shared__ float zs[4][16];
  int jg = blockIdx.x, b = blockIdx.y;
  int tid = threadIdx.x;
  int w = tid >> 6, l = tid & 63;
  int lr = l & 15, lg = l >> 4;
  int j0 = jg * 16;
  const u16* xbase = xb + (size_t)b * S * D;
  const u16* qbase = Qb + (size_t)b * S * D;
  bf16x8 xa0 = *(const bf16x8*)(xbase + (size_t)(j0 + lr) * D + lg * 8);
  bf16x8 xa1 = *(const bf16x8*)(xbase + (size_t)(j0 + lr) * D + 32 + lg * 8);
  float z[4] = {0.f, 0.f, 0.f, 0.f};
  for (int i16 = j0 + w * 16; i16 < S; i16 += 64) {
    bf16x8 q0 = *(const bf16x8*)(qbase + (size_t)(i16 + lr) * D + lg * 8);
    bf16x8 q1 = *(const bf16x8*)(qbase + (size_t)(i16 + lr) * D + 32 + lg * 8);
    f32x4 c = {};
    c = __builtin_amdgcn_mfma_f32_16x16x32_bf16(xa0, q0, c, 0, 0, 0);
    c = __builtin_amdgcn_mfma_f32_16x16x32_bf16(xa1, q1, c, 0, 0, 0);
    int i = i16 + lr;
#pragma unroll
    for (int r = 0; r < 4; ++r) {
      int j = j0 + lg * 4 + r;
      float sc = c[r];
      z[r] += (i >= j && sc > 1.0f) ? __expf(sc * SCL) : 0.f;
    }
  }
#pragma unroll
  for (int r = 0; r < 4; ++r) {
    z[r] += __shfl_xor(z[r], 1);
    z[r] += __shfl_xor(z[r], 2);
    z[r] += __shfl_xor(z[r], 4);
    z[r] += __shfl_xor(z[r], 8);
  }
  if (lr == 0) {
#pragma unroll
    for (int r = 0; r < 4; ++r) zs[w][lg * 4 + r] = z[r];
  }
  __syncthreads();
  if (tid < 16) {
    float zf = zs[0][tid] + zs[1][tid] + zs[2][tid] + zs[3][tid];
    rzbuf[(size_t)b * S + j0 + tid] = 1.0f / zf;
  }
}

// ---- N5: out += P_chunk @ V_chunk; P_ij = exp(sc*SCL)/Z_j (or 0) --------
__global__ __launch_bounds__(256) void k_out(
    const u16* __restrict__ xb, const u16* __restrict__ Qb, const u16* __restrict__ VTb,
    const float* __restrict__ rzbuf, float* __restrict__ out) {
  __shared__ u16 Plds[4][16][72];
  int bx = blockIdx.x, b = blockIdx.y;
  int it = 0, jc = 0, base = 0;
  for (int tt = 0; tt < 32; ++tt) {
    int nc = (tt + 4) >> 2;
    if (bx < base + nc) { it = tt; jc = bx - base; break; }
    base += nc;
  }
  int w = threadIdx.x >> 6, l = threadIdx.x & 63;
  int lr = l & 15, lg = l >> 4;
  int i0 = it * 64 + w * 16;
  const u16* xbase = xb + (size_t)b * S * D;
  const u16* qbase = Qb + (size_t)b * S * D;
  const u16* vbase = VTb + (size_t)b * D * S;
  const float* rzb = rzbuf + (size_t)b * S;
  bf16x8 qa0 = *(const bf16x8*)(qbase + (size_t)(i0 + lr) * D + lg * 8);
  bf16x8 qa1 = *(const bf16x8*)(qbase + (size_t)(i0 + lr) * D + 32 + lg * 8);
  f32x4 acc[4] = {};
  int jt_end = min(jc * 4 + 4, it + 1);
  for (int jt = jc * 4; jt < jt_end; ++jt) {
#pragma unroll
    for (int js = 0; js < 4; ++js) {
      int j16 = jt * 64 + js * 16;
      bf16x8 xb0 = *(const bf16x8*)(xbase + (size_t)(j16 + lr) * D + lg * 8);
      bf16x8 xb1 = *(const bf16x8*)(xbase + (size_t)(j16 + lr) * D + 32 + lg * 8);
      f32x4 c = {};
      c = __builtin_amdgcn_mfma_f32_16x16x32_bf16(qa0, xb0, c, 0, 0, 0);
      c = __builtin_amdgcn_mfma_f32_16x16x32_bf16(qa1, xb1, c, 0, 0, 0);
      int j = j16 + lr;
      float rzj = rzb[j];
#pragma unroll
      for (int r = 0; r < 4; ++r) {
        int i = i0 + lg * 4 + r;
        float sc = c[r];
        float wgt = (j <= i && sc > 1.0f) ? __expf(sc * SCL) * rzj : 0.f;
        Plds[w][lg * 4 + r][js * 16 + lr] = f2bf(wgt);
      }
    }
    asm volatile("s_waitcnt lgkmcnt(0)" ::: "memory");
#pragma unroll
    for (int kk = 0; kk < 2; ++kk) {
      bf16x8 pa = *(const bf16x8*)(&Plds[w][lr][kk * 32 + lg * 8]);
#pragma unroll
      for (int dt = 0; dt < 4; ++dt) {
        bf16x8 vbf = *(const bf16x8*)(vbase + (size_t)(dt * 16 + lr) * S + jt * 64 + kk * 32 + lg * 8);
        acc[dt] = __builtin_amdgcn_mfma_f32_16x16x32_bf16(pa, vbf, acc[dt], 0, 0, 0);
      }
    }
    asm volatile("s_waitcnt lgkmcnt(0)" ::: "memory");
  }
  float* obase = out + (size_t)b * S * D;
#pragma unroll
  for (int dt = 0; dt < 4; ++dt)
#pragma unroll
    for (int r = 0; r < 4; ++r) {
      int i = i0 + lg * 4 + r;
      atomicAdd(&obase[(size_t)i * D + dt * 16 + lr], acc[dt][r]);
    }
}

extern "C" void kernel_launch(void* const* d_in, const int* in_sizes, int n_in,
                              void* d_out, int out_size, void* d_ws, size_t ws_size,
                              hipStream_t stream) {
  const float* x  = (const float*)d_in[0];
  const float* wq = (const float*)d_in[1];
  const float* wv = (const float*)d_in[2];
  float* out = (float*)d_out;
  char* ws = (char*)d_ws;
  size_t off = 0;
  auto alloc = [&](size_t bytes) -> void* {
    void* p = ws + off; off += (bytes + 255) & ~255ULL; return p;
  };
  u16* xb   = (u16*)alloc((size_t)BATCH * S * D * 2);
  u16* xTb  = (u16*)alloc((size_t)BATCH * S * D * 2);
  u16* GTb  = (u16*)alloc((size_t)BATCH * S * D * 2);
  u16* Qb   = (u16*)alloc((size_t)BATCH * S * D * 2);
  u16* VTb  = (u16*)alloc((size_t)BATCH * S * D * 2);
  float* csum  = (float*)alloc((size_t)BATCH * 128 * 64 * 4);
  float* rzbuf = (float*)alloc((size_t)BATCH * S * 4);
  u16* wqb  = (u16*)alloc((size_t)S * S * 2);
  u16* wvb  = (u16*)alloc((size_t)S * S * 2);

  k_pre<<<4736, 256, 0, stream>>>(x, wq, wv, wqb, wvb, xb, xTb, csum, out);
  k_scanb<<<128, 256, 0, stream>>>(x, csum, GTb);
  k_wg<<<256, 256, 0, stream>>>(wqb, wvb, GTb, xTb, Qb, VTb);
  k_stats<<<dim3(128, BATCH), 256, 0, stream>>>(xb, Qb, rzbuf);
  k_out<<<dim3(144, BATCH), 256, 0, stream>>>(xb, Qb, VTb, rzbuf, out);
}

// Round 7
// 81.897 us; speedup vs baseline: 1.6967x; 1.3654x over previous
//
#include <hip/hip_runtime.h>

typedef unsigned short u16;
typedef __bf16 bf16;
typedef bf16 bf16x8 __attribute__((ext_vector_type(8)));
typedef float f32x4 __attribute__((ext_vector_type(4)));

#define S 2048
#define D 64
#define BATCH 4
#define SCL 0.022097086912079612f  /* 1/sqrt(2048) */

__device__ __forceinline__ u16 f2bf(float f) {
  union { float f; unsigned u; } v; v.f = f;
  return (u16)((v.u + 0x7FFFu + ((v.u >> 16) & 1u)) >> 16);
}

__device__ __forceinline__ void gld16(const u16* g, u16* l) {
  __builtin_amdgcn_global_load_lds(
      (const __attribute__((address_space(1))) unsigned int*)(const void*)g,
      (__attribute__((address_space(3))) unsigned int*)(void*)l, 16, 0, 0);
}

// ---- N1: fused pre. Q = W_Q@G == W'@x with W'[m,u] = suffix_{t>=u} W_Q[m,t]/(t+1).
// jobs: [0,512)   W' suffix-scan, 1 wave per row
//       [512,2560) W_V -> bf16
//       [2560,2688) x -> xb (row-major) + xTb (transposed), bf16
//       [2688,3200) zero d_out
__global__ void k_pre(const float* __restrict__ x,
                      const float* __restrict__ wq, const float* __restrict__ wv,
                      u16* __restrict__ wqp, u16* __restrict__ wvb,
                      u16* __restrict__ xb, u16* __restrict__ xTb,
                      float* __restrict__ out) {
  int bx = blockIdx.x, t = threadIdx.x;
  if (bx < 512) {                        // W' suffix scan
    int m = bx * 4 + (t >> 6);
    int l = t & 63;
    const float* row = wq + (size_t)m * S;
    u16* orow = wqp + (size_t)m * S;
    float carry = 0.f;
    for (int c = 31; c >= 0; --c) {
      int tt = c * 64 + l;
      float a = row[tt] / (float)(tt + 1);
      float s = a;
#pragma unroll
      for (int off = 1; off < 64; off <<= 1) {
        float o = __shfl_down(s, off);
        s += (l + off < 64) ? o : 0.f;
      }
      float tot = __shfl(s, 0);          // chunk total
      orow[tt] = f2bf(s + carry);
      carry += tot;
    }
  } else if (bx < 2560) {                // W_V convert
    size_t idx = ((size_t)(bx - 512) * 256 + t) * 8;
    const float* src = wv + idx;
    float4 a = *(const float4*)src;
    float4 b = *(const float4*)(src + 4);
    union { u16 s[8]; uint4 v; } u;
    u.s[0]=f2bf(a.x); u.s[1]=f2bf(a.y); u.s[2]=f2bf(a.z); u.s[3]=f2bf(a.w);
    u.s[4]=f2bf(b.x); u.s[5]=f2bf(b.y); u.s[6]=f2bf(b.z); u.s[7]=f2bf(b.w);
    *(uint4*)(wvb + idx) = u.v;
  } else if (bx < 2688) {                // x convert + transpose
    int job = (bx - 2560) * 4 + (t >> 6);
    int chunk = job >> 2, b = job & 3, d = t & 63;
    const float* xp = x + ((size_t)b * S + (size_t)chunk * 16) * D + d;
#pragma unroll
    for (int s = 0; s < 16; ++s) {
      float v = xp[(size_t)s * D];
      int sg = chunk * 16 + s;
      u16 h = f2bf(v);
      xb[((size_t)b * S + sg) * D + d] = h;
      xTb[((size_t)b * D + d) * S + sg] = h;
    }
  } else {                               // zero d_out
    size_t i = (((size_t)(bx - 2688) * 256) + t) * 4;
    *(float4*)(out + i) = make_float4(0.f, 0.f, 0.f, 0.f);
  }
}

// ---- N2: GEMMs Q = W'@x, V = W_V@x (shared B-panel xTb). Tile 64M x 32N,
// 128 threads (2 waves x 32Mx32N), BK=64, 512 blocks = 2/CU.
__global__ __launch_bounds__(128) void k_wg(
    const u16* __restrict__ wqp, const u16* __restrict__ wvb,
    const u16* __restrict__ xTb,
    u16* __restrict__ Qb, u16* __restrict__ VTb) {
  __shared__ u16 Ab[2][64 * 64];  // 16 KB
  __shared__ u16 Bb[2][32 * 64];  // 8 KB
  int bx = blockIdx.x;            // nt*64 + mt*2 + mat : B-panel shared across 64
  int nt = bx >> 6, mm = bx & 63, mt = mm >> 1, mat = mm & 1;
  int t = threadIdx.x;
  int w = t >> 6, l = t & 63;
  int lr = l & 15, lg = l >> 4;
  const u16* A = (mat ? wvb : wqp) + (size_t)(mt * 64) * S;
  const u16* BT = xTb + (size_t)(nt * 32) * S;
  int rA = t >> 3;                 // 0..15: row within a 16-row issue
  int sb = t & 7;                  // 16B slot
  int swz = (sb ^ (rA & 7)) * 8;   // pre-swizzled source column
  const u16* Ag = A + (size_t)rA * S + swz;
  const u16* Bg = BT + (size_t)rA * S + swz;
  f32x4 acc[2][2] = {};

  auto stage = [&](int buf, int kt) {
#pragma unroll
    for (int i = 0; i < 4; ++i)
      gld16(Ag + kt * 64 + (size_t)i * 16 * S, &Ab[buf][i * 1024 + t * 8]);
#pragma unroll
    for (int i = 0; i < 2; ++i)
      gld16(Bg + kt * 64 + (size_t)i * 16 * S, &Bb[buf][i * 1024 + t * 8]);
  };

  stage(0, 0);
  __syncthreads();
  int buf = 0;
  for (int kt = 0; kt < 32; ++kt) {
    if (kt < 31) stage(buf ^ 1, kt + 1);
    bf16x8 af[2][2], bfv[2][2];
#pragma unroll
    for (int mf = 0; mf < 2; ++mf)
#pragma unroll
      for (int ks = 0; ks < 2; ++ks) {
        int row = w * 32 + mf * 16 + lr;
        af[mf][ks] = *(const bf16x8*)&Ab[buf][row * 64 + (((ks * 4 + lg) ^ (lr & 7)) * 8)];
      }
#pragma unroll
    for (int nf = 0; nf < 2; ++nf)
#pragma unroll
      for (int ks = 0; ks < 2; ++ks) {
        int row = nf * 16 + lr;
        bfv[nf][ks] = *(const bf16x8*)&Bb[buf][row * 64 + (((ks * 4 + lg) ^ (lr & 7)) * 8)];
      }
#pragma unroll
    for (int ks = 0; ks < 2; ++ks)
#pragma unroll
      for (int mf = 0; mf < 2; ++mf)
#pragma unroll
        for (int nf = 0; nf < 2; ++nf)
          acc[mf][nf] = __builtin_amdgcn_mfma_f32_16x16x32_bf16(af[mf][ks], bfv[nf][ks], acc[mf][nf], 0, 0, 0);
    __syncthreads();
    buf ^= 1;
  }
  // epilogue: m = mt*64 + w*32 + mf*16 + lg*4 + r ; n = nt*32 + nf*16 + lr
  // b = n>>6, d = n&63
#pragma unroll
  for (int mf = 0; mf < 2; ++mf) {
    int mbase = mt * 64 + w * 32 + mf * 16 + lg * 4;
#pragma unroll
    for (int nf = 0; nf < 2; ++nf) {
      int n = nt * 32 + nf * 16 + lr;
      int b = n >> 6, d = n & 63;
      if (mat == 0) {
#pragma unroll
        for (int r = 0; r < 4; ++r)
          Qb[((size_t)b * S + mbase + r) * D + d] = f2bf(acc[mf][nf][r]);
      } else {
        union { u16 s[4]; ushort4 v; } u;
#pragma unroll
        for (int r = 0; r < 4; ++r) u.s[r] = f2bf(acc[mf][nf][r]);
        *(ushort4*)&VTb[((size_t)b * D + d) * S + mbase] = u.v;
      }
    }
  }
}

// ---- N3: column sums Z_j = sum_{i>=j, sc>1} exp(sc*SCL) (no-max: bounded).
// jg ascending = heavy-first already.
__global__ __launch_bounds__(256) void k_stats(
    const u16* __restrict__ xb, const u16* __restrict__ Qb,
    float* __restrict__ rzbuf) {
  __shared__ float zs[4][16];
  int jg = blockIdx.x, b = blockIdx.y;
  int tid = threadIdx.x;
  int w = tid >> 6, l = tid & 63;
  int lr = l & 15, lg = l >> 4;
  int j0 = jg * 16;
  const u16* xbase = xb + (size_t)b * S * D;
  const u16* qbase = Qb + (size_t)b * S * D;
  bf16x8 xa0 = *(const bf16x8*)(xbase + (size_t)(j0 + lr) * D + lg * 8);
  bf16x8 xa1 = *(const bf16x8*)(xbase + (size_t)(j0 + lr) * D + 32 + lg * 8);
  float z[4] = {0.f, 0.f, 0.f, 0.f};
  for (int i16 = j0 + w * 16; i16 < S; i16 += 64) {
    bf16x8 q0 = *(const bf16x8*)(qbase + (size_t)(i16 + lr) * D + lg * 8);
    bf16x8 q1 = *(const bf16x8*)(qbase + (size_t)(i16 + lr) * D + 32 + lg * 8);
    f32x4 c = {};
    c = __builtin_amdgcn_mfma_f32_16x16x32_bf16(xa0, q0, c, 0, 0, 0);
    c = __builtin_amdgcn_mfma_f32_16x16x32_bf16(xa1, q1, c, 0, 0, 0);
    int i = i16 + lr;
#pragma unroll
    for (int r = 0; r < 4; ++r) {
      int j = j0 + lg * 4 + r;
      float sc = c[r];
      z[r] += (i >= j && sc > 1.0f) ? __expf(sc * SCL) : 0.f;
    }
  }
#pragma unroll
  for (int r = 0; r < 4; ++r) {
    z[r] += __shfl_xor(z[r], 1);
    z[r] += __shfl_xor(z[r], 2);
    z[r] += __shfl_xor(z[r], 4);
    z[r] += __shfl_xor(z[r], 8);
  }
  if (lr == 0) {
#pragma unroll
    for (int r = 0; r < 4; ++r) zs[w][lg * 4 + r] = z[r];
  }
  __syncthreads();
  if (tid < 16) {
    float zf = zs[0][tid] + zs[1][tid] + zs[2][tid] + zs[3][tid];
    rzbuf[(size_t)b * S + j0 + tid] = 1.0f / zf;
  }
}

// ---- N4: out += P_chunk @ V_chunk; P_ij = exp(sc*SCL)/Z_j (or 0).
// Reversed decode: heavy i-tiles dispatch first.
__global__ __launch_bounds__(256) void k_out(
    const u16* __restrict__ xb, const u16* __restrict__ Qb, const u16* __restrict__ VTb,
    const float* __restrict__ rzbuf, float* __restrict__ out) {
  __shared__ u16 Plds[4][16][72];
  int bx = 143 - blockIdx.x, b = blockIdx.y;   // heavy-first
  int it = 0, jc = 0, base = 0;
  for (int tt = 0; tt < 32; ++tt) {
    int nc = (tt + 4) >> 2;
    if (bx < base + nc) { it = tt; jc = bx - base; break; }
    base += nc;
  }
  int w = threadIdx.x >> 6, l = threadIdx.x & 63;
  int lr = l & 15, lg = l >> 4;
  int i0 = it * 64 + w * 16;
  const u16* xbase = xb + (size_t)b * S * D;
  const u16* qbase = Qb + (size_t)b * S * D;
  const u16* vbase = VTb + (size_t)b * D * S;
  const float* rzb = rzbuf + (size_t)b * S;
  bf16x8 qa0 = *(const bf16x8*)(qbase + (size_t)(i0 + lr) * D + lg * 8);
  bf16x8 qa1 = *(const bf16x8*)(qbase + (size_t)(i0 + lr) * D + 32 + lg * 8);
  f32x4 acc[4] = {};
  int jt_end = min(jc * 4 + 4, it + 1);
  for (int jt = jc * 4; jt < jt_end; ++jt) {
#pragma unroll
    for (int js = 0; js < 4; ++js) {
      int j16 = jt * 64 + js * 16;
      bf16x8 xb0 = *(const bf16x8*)(xbase + (size_t)(j16 + lr) * D + lg * 8);
      bf16x8 xb1 = *(const bf16x8*)(xbase + (size_t)(j16 + lr) * D + 32 + lg * 8);
      f32x4 c = {};
      c = __builtin_amdgcn_mfma_f32_16x16x32_bf16(qa0, xb0, c, 0, 0, 0);
      c = __builtin_amdgcn_mfma_f32_16x16x32_bf16(qa1, xb1, c, 0, 0, 0);
      int j = j16 + lr;
      float rzj = rzb[j];
#pragma unroll
      for (int r = 0; r < 4; ++r) {
        int i = i0 + lg * 4 + r;
        float sc = c[r];
        float wgt = (j <= i && sc > 1.0f) ? __expf(sc * SCL) * rzj : 0.f;
        Plds[w][lg * 4 + r][js * 16 + lr] = f2bf(wgt);
      }
    }
    asm volatile("s_waitcnt lgkmcnt(0)" ::: "memory");
#pragma unroll
    for (int kk = 0; kk < 2; ++kk) {
      bf16x8 pa = *(const bf16x8*)(&Plds[w][lr][kk * 32 + lg * 8]);
#pragma unroll
      for (int dt = 0; dt < 4; ++dt) {
        bf16x8 vbf = *(const bf16x8*)(vbase + (size_t)(dt * 16 + lr) * S + jt * 64 + kk * 32 + lg * 8);
        acc[dt] = __builtin_amdgcn_mfma_f32_16x16x32_bf16(pa, vbf, acc[dt], 0, 0, 0);
      }
    }
    asm volatile("s_waitcnt lgkmcnt(0)" ::: "memory");
  }
  float* obase = out + (size_t)b * S * D;
#pragma unroll
  for (int dt = 0; dt < 4; ++dt)
#pragma unroll
    for (int r = 0; r < 4; ++r) {
      int i = i0 + lg * 4 + r;
      atomicAdd(&obase[(size_t)i * D + dt * 16 + lr], acc[dt][r]);
    }
}

extern "C" void kernel_launch(void* const* d_in, const int* in_sizes, int n_in,
                              void* d_out, int out_size, void* d_ws, size_t ws_size,
                              hipStream_t stream) {
  const float* x  = (const float*)d_in[0];
  const float* wq = (const float*)d_in[1];
  const float* wv = (const float*)d_in[2];
  float* out = (float*)d_out;
  char* ws = (char*)d_ws;
  size_t off = 0;
  auto alloc = [&](size_t bytes) -> void* {
    void* p = ws + off; off += (bytes + 255) & ~255ULL; return p;
  };
  u16* xb   = (u16*)alloc((size_t)BATCH * S * D * 2);
  u16* xTb  = (u16*)alloc((size_t)BATCH * S * D * 2);
  u16* Qb   = (u16*)alloc((size_t)BATCH * S * D * 2);
  u16* VTb  = (u16*)alloc((size_t)BATCH * S * D * 2);
  float* rzbuf = (float*)alloc((size_t)BATCH * S * 4);
  u16* wqp  = (u16*)alloc((size_t)S * S * 2);   // W' = W_Q @ L (suffix-scanned)
  u16* wvb  = (u16*)alloc((size_t)S * S * 2);

  k_pre<<<3200, 256, 0, stream>>>(x, wq, wv, wqp, wvb, xb, xTb, out);
  k_wg<<<512, 128, 0, stream>>>(wqp, wvb, xTb, Qb, VTb);
  k_stats<<<dim3(128, BATCH), 256, 0, stream>>>(xb, Qb, rzbuf);
  k_out<<<dim3(144, BATCH), 256, 0, stream>>>(xb, Qb, VTb, rzbuf, out);
}